// Round 8
// baseline (173.239 us; speedup 1.0000x reference)
//
#include <hip/hip_runtime.h>
#include <math.h>

constexpr int Bb = 2;
constexpr int Nn = 2048;
constexpr int Cc = 512;
constexpr int Hh = 8;
constexpr int Dd = 64;

typedef short short8 __attribute__((ext_vector_type(8)));
typedef float floatx4 __attribute__((ext_vector_type(4)));
typedef float floatx16 __attribute__((ext_vector_type(16)));

__device__ inline short8 bcs8(uint4 u) { return __builtin_bit_cast(short8, u); }
__device__ inline float4 bcf4(uint4 u) { return __builtin_bit_cast(float4, u); }

__device__ inline floatx4 mfma16(short8 a, short8 b, floatx4 c) {
    return __builtin_amdgcn_mfma_f32_16x16x32_bf16(a, b, c, 0, 0, 0);
}
__device__ inline floatx16 mfma32(short8 a, short8 b, floatx16 c) {
    return __builtin_amdgcn_mfma_f32_32x32x16_bf16(a, b, c, 0, 0, 0);
}

// async global->LDS, 16B per lane, dest = uniform base + lane*16
typedef __attribute__((address_space(1))) void gvoid;
typedef __attribute__((address_space(3))) void svoid;
__device__ inline void glds16(const void* g, void* l) {
    __builtin_amdgcn_global_load_lds((const gvoid*)g, (svoid*)l, 16, 0, 0);
}

#if __has_builtin(__builtin_amdgcn_exp2f)
#define EXP2(x) __builtin_amdgcn_exp2f(x)
#else
#define EXP2(x) __expf((x) * 0.69314718056f)
#endif

// pack bf16(a)|bf16(b)<<16, truncation (hi/lo splits: lo compensates hi)
__device__ inline unsigned pk_trunc(float a, float b) {
    return __builtin_amdgcn_perm(__float_as_uint(b), __float_as_uint(a), 0x07060302u);
}
// RNE pack
__device__ inline unsigned pk_rne(float a, float b) {
    unsigned ua = __float_as_uint(a); ua += 0x7fffu + ((ua >> 16) & 1u);
    unsigned ub = __float_as_uint(b); ub += 0x7fffu + ((ub >> 16) & 1u);
    return __builtin_amdgcn_perm(ub, ua, 0x07060302u);
}
__device__ inline unsigned short rne1(float a) {
    unsigned u = __float_as_uint(a); u += 0x7fffu + ((u >> 16) & 1u);
    return (unsigned short)(u >> 16);
}
__device__ inline float tr16(float a) {
    return __uint_as_float(__float_as_uint(a) & 0xffff0000u);
}
__device__ inline void split8(float4 A, float4 B, uint4& hi, uint4& lo) {
    hi = make_uint4(pk_trunc(A.x, A.y), pk_trunc(A.z, A.w),
                    pk_trunc(B.x, B.y), pk_trunc(B.z, B.w));
    lo = make_uint4(pk_trunc(A.x - tr16(A.x), A.y - tr16(A.y)),
                    pk_trunc(A.z - tr16(A.z), A.w - tr16(A.w)),
                    pk_trunc(B.x - tr16(B.x), B.y - tr16(B.y)),
                    pk_trunc(B.z - tr16(B.z), B.w - tr16(B.w)));
}

// ---------------------------------------------------------------------------
// prep: weight transpose + hi/lo split only (x split moved into gemm_qkv).
// grid 256 x 256thr.
// ---------------------------------------------------------------------------
__global__ __launch_bounds__(256) void prep(const float* __restrict__ qkv_w,
                                            const float* __restrict__ proj_w,
                                            unsigned short* __restrict__ wqh,
                                            unsigned short* __restrict__ wql,
                                            unsigned short* __restrict__ wph,
                                            unsigned short* __restrict__ wpl)
{
    __shared__ float Tl[64][68];
    int bid = blockIdx.x;
    const float* src; unsigned short *dh, *dlo; int W, f0, k0;
    if (bid < 192) { int kt = bid / 24, ft = bid % 24; W = 1536; src = qkv_w; dh = wqh; dlo = wql; f0 = ft * 64; k0 = kt * 64; }
    else { int b2 = bid - 192; int kt = b2 / 8, ft = b2 % 8; W = 512; src = proj_w; dh = wph; dlo = wpl; f0 = ft * 64; k0 = kt * 64; }
    int t = threadIdx.x;
    {
        int kl = t >> 2, fc = (t & 3) * 16;
        const float* p = src + (size_t)(k0 + kl) * W + f0 + fc;
        #pragma unroll
        for (int i = 0; i < 4; ++i) {
            float4 v = *(const float4*)(p + i * 4);
            Tl[kl][fc + i * 4 + 0] = v.x; Tl[kl][fc + i * 4 + 1] = v.y;
            Tl[kl][fc + i * 4 + 2] = v.z; Tl[kl][fc + i * 4 + 3] = v.w;
        }
    }
    __syncthreads();
    {
        int fl = t >> 2, kc = (t & 3) * 16;
        float v[16];
        #pragma unroll
        for (int i = 0; i < 16; ++i) v[i] = Tl[kc + i][fl];
        unsigned hi[8], lo[8];
        #pragma unroll
        for (int i = 0; i < 8; ++i) {
            float a = v[2 * i], b = v[2 * i + 1];
            hi[i] = pk_trunc(a, b);
            lo[i] = pk_trunc(a - tr16(a), b - tr16(b));
        }
        unsigned short* oh = dh + (size_t)(f0 + fl) * 512 + k0 + kc;
        unsigned short* ol = dlo + (size_t)(f0 + fl) * 512 + k0 + kc;
        *(uint4*)oh = make_uint4(hi[0], hi[1], hi[2], hi[3]);
        *(uint4*)(oh + 8) = make_uint4(hi[4], hi[5], hi[6], hi[7]);
        *(uint4*)ol = make_uint4(lo[0], lo[1], lo[2], lo[3]);
        *(uint4*)(ol + 8) = make_uint4(lo[4], lo[5], lo[6], lo[7]);
    }
}

// ---------------------------------------------------------------------------
// GEMM1: x(fp32, staged+split in-kernel) @ qkv_w(split,T) -> dense
// qd/kd[bh][n][64] + vt[bh][d][n]. q pre-scaled by 0.125*log2(e).
// BM=128 BN=64, pipelined BK=32 stages (2 x 24 KB LDS), 256 thr, grid (24,32).
// A staged fp32 in FRAGMENT order: seg(mt,sub): lane l -> x[row0+mt*16+(l&15)]
// [k0+(l>>4)*8+sub*4 .. +4) ; frag read = 2 conflict-free b128 + VALU split.
// ---------------------------------------------------------------------------
__global__ __launch_bounds__(256, 3) void gemm_qkv(const float* __restrict__ x,
                                                   const unsigned short* __restrict__ wh,
                                                   const unsigned short* __restrict__ wl,
                                                   unsigned short* __restrict__ qd,
                                                   unsigned short* __restrict__ kd,
                                                   unsigned short* __restrict__ vt)
{
    __shared__ __align__(16) char smem[49152];   // 2 x [A 16K | Bh 4K | Bl 4K]
    const int tid = threadIdx.x, lane = tid & 63, w = tid >> 6;
    const int l15 = lane & 15, l4 = lane >> 4;
    const int row0 = blockIdx.y * 128, col0 = blockIdx.x * 64;
    const int wm = w >> 1, wn = w & 1;

    floatx4 acc[4][2];
    #pragma unroll
    for (int i = 0; i < 4; ++i)
        #pragma unroll
        for (int j = 0; j < 2; ++j)
            #pragma unroll
            for (int r = 0; r < 4; ++r) acc[i][j][r] = 0.f;

    auto stage = [&](int k0, char* buf) {
        #pragma unroll
        for (int i = 0; i < 4; ++i) {            // A: 16 segs (mt8 x sub2), fp32
            int sid = w * 4 + i; int mt = sid >> 1, sub = sid & 1;
            const float* src = x + (size_t)(row0 + mt * 16 + l15) * 512 + k0 + l4 * 8 + sub * 4;
            glds16(src, buf + sid * 1024);
        }
        #pragma unroll
        for (int i = 0; i < 2; ++i) {            // B: 8 segs (4 nt x hi/lo)
            int sid = w * 2 + i; int nt = sid >> 1, comp = sid & 1;
            const unsigned short* src = (comp ? wl : wh) + (size_t)(col0 + nt * 16 + l15) * 512 + k0 + l4 * 8;
            glds16(src, buf + 16384 + comp * 4096 + nt * 1024);
        }
    };

    stage(0, smem);
    for (int it = 0; it < 16; ++it) {
        __syncthreads();                          // drains stage(it); prev readers done
        char* buf = smem + (it & 1) * 24576;
        if (it < 15) stage((it + 1) * 32, smem + ((it + 1) & 1) * 24576);
        char* Ab = buf; char* Bh = buf + 16384; char* Bl = buf + 20480;
        short8 af[4][2], bf[2][2];
        #pragma unroll
        for (int mt = 0; mt < 4; ++mt) {
            int off = (((wm * 4 + mt) * 2) << 10) + (lane << 4);
            float4 fa = bcf4(*(const uint4*)(Ab + off));
            float4 fb = bcf4(*(const uint4*)(Ab + off + 1024));
            uint4 hi, lo;
            split8(fa, fb, hi, lo);
            af[mt][0] = bcs8(hi);
            af[mt][1] = bcs8(lo);
        }
        #pragma unroll
        for (int nt = 0; nt < 2; ++nt) {
            int off = ((wn * 2 + nt) << 10) + (lane << 4);
            bf[nt][0] = bcs8(*(const uint4*)(Bh + off));
            bf[nt][1] = bcs8(*(const uint4*)(Bl + off));
        }
        #pragma unroll
        for (int mt = 0; mt < 4; ++mt)
            #pragma unroll
            for (int nt = 0; nt < 2; ++nt) {
                acc[mt][nt] = mfma16(af[mt][0], bf[nt][0], acc[mt][nt]);
                acc[mt][nt] = mfma16(af[mt][0], bf[nt][1], acc[mt][nt]);
                acc[mt][nt] = mfma16(af[mt][1], bf[nt][0], acc[mt][nt]);
            }
    }
    // epilogue: q (scaled, with log2e folded), k dense; v written transposed
    #pragma unroll
    for (int mt = 0; mt < 4; ++mt)
        #pragma unroll
        for (int nt = 0; nt < 2; ++nt) {
            int c = col0 + (wn * 2 + nt) * 16 + l15;     // 0..1535
            int which = c >> 9;                          // 0=q,1=k,2=v (block-uniform)
            int head = (c >> 6) & 7, d = c & 63;
            int tokb = row0 + (wm * 4 + mt) * 16 + l4 * 4;
            int b = tokb >> 11, n = tokb & 2047;
            if (which == 2) {
                uint2 pv;
                pv.x = pk_rne(acc[mt][nt][0], acc[mt][nt][1]);
                pv.y = pk_rne(acc[mt][nt][2], acc[mt][nt][3]);
                *(uint2*)&vt[((size_t)((b * 8 + head) * 64 + d)) * 2048 + n] = pv;
            } else {
                unsigned short* dst = which ? kd : qd;
                float s = which ? 1.0f : 0.18033688f;    // 0.125 * log2(e)
                #pragma unroll
                for (int r = 0; r < 4; ++r)
                    dst[(size_t)((b * 8 + head) * 2048 + n + r) * 64 + d] = rne1(acc[mt][nt][r] * s);
            }
        }
}

// ---------------------------------------------------------------------------
// Attention: V double-buffered in LDS (2 x 16 KB); K loaded DIRECT to
// registers (dense 128B rows, register double-buffered, prefetched right
// after each barrier). 512 thr = 8 waves (qg2 x kg4), 128-key chunks,
// grid 512 (16 bh x 32 qtiles, XCD-swizzled). S^T = K.Q^T (mfma32, log2e
// folded into Q -> raw exp2); P trunc-packed; l via all-ones MFMA; P
// transform uses 2 shuffles/kc (T-trick). One LDS merge at end.
// ---------------------------------------------------------------------------
__global__ __launch_bounds__(512, 4) void attn(const unsigned short* __restrict__ qd,
                                               const unsigned short* __restrict__ kd,
                                               const unsigned short* __restrict__ vt,
                                               unsigned short* __restrict__ Oh,
                                               unsigned short* __restrict__ Ol)
{
    __shared__ __align__(16) char smem[51200];   // V dbuf 32K | merge overlays

    int bid = blockIdx.x;
    int xcd = bid & 7; int rr = bid >> 3;
    int qt = rr & 31; int bhi = rr >> 5;
    int bh = (bhi << 3) | xcd;
    int tid = threadIdx.x, lane = tid & 63, w = tid >> 6;
    int qg = w >> 2, kg = w & 3;
    int l31 = lane & 31, h = lane >> 5;

    // Q^T fragments (B-operand), once from dense qd (pre-scaled, log2e folded)
    short8 qf[4];
    #pragma unroll
    for (int s = 0; s < 4; ++s)
        qf[s] = bcs8(*(const uint4*)(qd + ((size_t)bh * 2048 + qt * 64 + qg * 32 + l31) * 64 + s * 16 + h * 8));

    const uint4 onesu = make_uint4(0x3F803F80u, 0x3F803F80u, 0x3F803F80u, 0x3F803F80u);
    const short8 onesf = bcs8(onesu);

    floatx16 OT[2], OTl;
    #pragma unroll
    for (int i = 0; i < 2; ++i)
        #pragma unroll
        for (int r = 0; r < 16; ++r) OT[i][r] = 0.f;
    #pragma unroll
    for (int r = 0; r < 16; ++r) OTl[r] = 0.f;

    // V stage: chunk c -> 16 segs of 1 KB (mtv2 x sv8), 2 per wave
    auto stageV = [&](int c, char* buf) {
        int ks0 = c * 128;
        #pragma unroll
        for (int i = 0; i < 2; ++i) {
            int sid = w * 2 + i; int mtv = sid >> 3, sv = sid & 7;
            const unsigned short* src = vt + (size_t)(bh * 64 + mtv * 32 + l31) * 2048 + ks0 + sv * 16 + h * 8;
            glds16(src, buf + sid * 1024);
        }
    };

    // K direct: per-lane base for this wave's 32-key group; chunk stride 128 rows
    const unsigned short* kb_ = kd + ((size_t)bh * 2048 + kg * 32 + l31) * 64 + h * 8;
    uint4 kfb[2][4];
    #pragma unroll
    for (int s = 0; s < 4; ++s) kfb[0][s] = *(const uint4*)(kb_ + s * 16);
    stageV(0, smem);

    #pragma unroll
    for (int c = 0; c < 16; ++c) {
        __syncthreads();                          // drains stageV(c)+K(c); prev readers done
        const int cur = c & 1;
        char* Vst = smem + cur * 16384;
        if (c < 15) {
            stageV(c + 1, smem + (cur ^ 1) * 16384);
            const unsigned short* kp = kb_ + (size_t)(c + 1) * 128 * 64;
            #pragma unroll
            for (int s = 0; s < 4; ++s) kfb[cur ^ 1][s] = *(const uint4*)(kp + s * 16);
        }

        short8 vf[2][2];
        #pragma unroll
        for (int kc = 0; kc < 2; ++kc) {
            int sv = kg * 2 + kc;
            vf[kc][0] = bcs8(*(const uint4*)(Vst + sv * 1024 + (lane << 4)));
            vf[kc][1] = bcs8(*(const uint4*)(Vst + (8 + sv) * 1024 + (lane << 4)));
        }

        floatx16 st;
        #pragma unroll
        for (int r = 0; r < 16; ++r) st[r] = 0.f;
        #pragma unroll
        for (int s = 0; s < 4; ++s) st = mfma32(bcs8(kfb[cur][s]), qf[s], st);

        // exp2 (log2e pre-folded), truncation pack (bias cancels via MFMA-l)
        unsigned P2[8];
        #pragma unroll
        for (int s2 = 0; s2 < 8; ++s2)
            P2[s2] = pk_trunc(EXP2(st[2 * s2]), EXP2(st[2 * s2 + 1]));

        #pragma unroll
        for (int kc = 0; kc < 2; ++kc) {
            unsigned X0 = P2[4 * kc + 0], X1 = P2[4 * kc + 1];
            unsigned Y0 = P2[4 * kc + 2], Y1 = P2[4 * kc + 3];
            // T-trick: one shuffle pair recovers both cross-half values
            unsigned T0 = h ? X0 : Y0;
            unsigned T1 = h ? X1 : Y1;
            unsigned To0 = __shfl_xor(T0, 32, 64);
            unsigned To1 = __shfl_xor(T1, 32, 64);
            uint4 fu;
            fu.x = h ? To0 : X0;
            fu.y = h ? To1 : X1;
            fu.z = h ? Y0 : To0;
            fu.w = h ? Y1 : To1;
            short8 pf = bcs8(fu);
            OT[0] = mfma32(vf[kc][0], pf, OT[0]);
            OT[1] = mfma32(vf[kc][1], pf, OT[1]);
            OTl = mfma32(onesf, pf, OTl);         // l += column-sums of rounded P
        }
    }

    // ---- merge partial O/l across the 4 kg waves, per qg ----
    float* Mq = (float*)smem + qg * 2048;                   // [d(64)][q(32)] @0, 16KB
    float* Lq = (float*)(smem + 32768) + qg * 64;           // [h(2)][q(32)] dup halves
    float* Tq = (float*)(smem + 33280) + qg * 2176;         // [q(32)][68]

    __syncthreads();                              // K-loop fully done before overlay
    if (kg == 3) {
        #pragma unroll
        for (int mtv = 0; mtv < 2; ++mtv)
            #pragma unroll
            for (int r = 0; r < 16; ++r) {
                int d = mtv * 32 + (r & 3) + 8 * (r >> 2) + 4 * h;
                Mq[d * 32 + l31] = OT[mtv][r];
            }
        Lq[h * 32 + l31] = OTl[0];
    }
    __syncthreads();
    if (kg == 2) {
        #pragma unroll
        for (int mtv = 0; mtv < 2; ++mtv)
            #pragma unroll
            for (int r = 0; r < 16; ++r) {
                int d = mtv * 32 + (r & 3) + 8 * (r >> 2) + 4 * h;
                Mq[d * 32 + l31] += OT[mtv][r];
            }
        Lq[h * 32 + l31] += OTl[0];
    }
    __syncthreads();
    if (kg == 1) {
        #pragma unroll
        for (int mtv = 0; mtv < 2; ++mtv)
            #pragma unroll
            for (int r = 0; r < 16; ++r) {
                int d = mtv * 32 + (r & 3) + 8 * (r >> 2) + 4 * h;
                Mq[d * 32 + l31] += OT[mtv][r];
            }
        Lq[h * 32 + l31] += OTl[0];
    }
    __syncthreads();
    if (kg == 0) {
        #pragma unroll
        for (int mtv = 0; mtv < 2; ++mtv)
            #pragma unroll
            for (int r = 0; r < 16; ++r) {
                int d = mtv * 32 + (r & 3) + 8 * (r >> 2) + 4 * h;
                OT[mtv][r] += Mq[d * 32 + l31];
            }
        float inv = 1.f / (Lq[h * 32 + l31] + OTl[0]);      // both halves identical
        #pragma unroll
        for (int mtv = 0; mtv < 2; ++mtv)
            #pragma unroll
            for (int r = 0; r < 16; ++r) {
                int d = mtv * 32 + (r & 3) + 8 * (r >> 2) + 4 * h;
                Tq[l31 * 68 + d] = OT[mtv][r] * inv;
            }
    }
    __syncthreads();
    // all 512 threads: coalesced split-bf16 store of O (flat B,H,N,D)
    {
        int q = tid >> 3, dc = (tid & 7) * 8;               // q 0..63
        const float* T = (const float*)(smem + 33280) + (q >> 5) * 2176;
        int ql = q & 31;
        float vv[8];
        #pragma unroll
        for (int i = 0; i < 8; ++i) vv[i] = T[ql * 68 + dc + i];
        unsigned hi[4], lo[4];
        #pragma unroll
        for (int i = 0; i < 4; ++i) {
            float a = vv[2 * i], bb = vv[2 * i + 1];
            hi[i] = pk_trunc(a, bb);
            lo[i] = pk_trunc(a - tr16(a), bb - tr16(bb));
        }
        size_t bo = ((size_t)(bh * 2048 + qt * 64 + q)) * 64 + dc;
        *(uint4*)(Oh + bo) = make_uint4(hi[0], hi[1], hi[2], hi[3]);
        *(uint4*)(Ol + bo) = make_uint4(lo[0], lo[1], lo[2], lo[3]);
    }
}

// ---------------------------------------------------------------------------
// GEMM2: out = O(split) @ proj_w(split,T) + bias. BM=64 BN=64, pipelined
// BK=32 stages (2 x 16 KB LDS). 256 thr = 4 waves of 32x32. grid (8,64).
// ---------------------------------------------------------------------------
__global__ __launch_bounds__(256, 2) void gemm_proj(const unsigned short* __restrict__ Ah_g,
                                                    const unsigned short* __restrict__ Al_g,
                                                    const unsigned short* __restrict__ wh,
                                                    const unsigned short* __restrict__ wl,
                                                    const float* __restrict__ bias,
                                                    float* __restrict__ out)
{
    __shared__ __align__(16) char smem[32768];   // 2 x [Ah 4K | Al 4K | Bh 4K | Bl 4K]
    const int tid = threadIdx.x, lane = tid & 63, w = tid >> 6;
    const int l15 = lane & 15, l4 = lane >> 4;
    const int row0 = blockIdx.y * 64, col0 = blockIdx.x * 64;
    const int wm = w >> 1, wn = w & 1;

    floatx4 acc[2][2];
    #pragma unroll
    for (int i = 0; i < 2; ++i)
        #pragma unroll
        for (int j = 0; j < 2; ++j)
            #pragma unroll
            for (int r = 0; r < 4; ++r) acc[i][j][r] = 0.f;

    auto stage = [&](int k0, char* buf) {
        #pragma unroll
        for (int i = 0; i < 4; ++i) {            // 16 segs: 8 A + 8 B
            int sid = w * 4 + i;
            if (sid < 8) {
                int mt = sid >> 1, comp = sid & 1;
                const unsigned short* src = (comp ? Al_g : Ah_g) + (size_t)(row0 + mt * 16 + l15) * 512 + k0 + l4 * 8;
                glds16(src, buf + (comp ? 4096 : 0) + mt * 1024);
            } else {
                int s2 = sid - 8; int nt = s2 >> 1, comp = s2 & 1;
                const unsigned short* src = (comp ? wl : wh) + (size_t)(col0 + nt * 16 + l15) * 512 + k0 + l4 * 8;
                glds16(src, buf + (comp ? 12288 : 8192) + nt * 1024);
            }
        }
    };

    stage(0, smem);
    for (int it = 0; it < 16; ++it) {
        __syncthreads();
        char* buf = smem + (it & 1) * 16384;
        if (it < 15) stage((it + 1) * 32, smem + ((it + 1) & 1) * 16384);
        char* Ah = buf; char* Al = buf + 4096; char* Bh = buf + 8192; char* Bl = buf + 12288;
        short8 af[2][2], bf[2][2];
        #pragma unroll
        for (int mt = 0; mt < 2; ++mt) {
            int off = ((wm * 2 + mt) << 10) + (lane << 4);
            af[mt][0] = bcs8(*(const uint4*)(Ah + off));
            af[mt][1] = bcs8(*(const uint4*)(Al + off));
        }
        #pragma unroll
        for (int nt = 0; nt < 2; ++nt) {
            int off = ((wn * 2 + nt) << 10) + (lane << 4);
            bf[nt][0] = bcs8(*(const uint4*)(Bh + off));
            bf[nt][1] = bcs8(*(const uint4*)(Bl + off));
        }
        #pragma unroll
        for (int mt = 0; mt < 2; ++mt)
            #pragma unroll
            for (int nt = 0; nt < 2; ++nt) {
                acc[mt][nt] = mfma16(af[mt][0], bf[nt][0], acc[mt][nt]);
                acc[mt][nt] = mfma16(af[mt][0], bf[nt][1], acc[mt][nt]);
                acc[mt][nt] = mfma16(af[mt][1], bf[nt][0], acc[mt][nt]);
            }
    }
    #pragma unroll
    for (int mt = 0; mt < 2; ++mt)
        #pragma unroll
        for (int nt = 0; nt < 2; ++nt) {
            int c = col0 + (wn * 2 + nt) * 16 + l15;
            float bv = bias[c];
            #pragma unroll
            for (int r = 0; r < 4; ++r) {
                int tok = row0 + (wm * 2 + mt) * 16 + l4 * 4 + r;
                out[(size_t)tok * 512 + c] = acc[mt][nt][r] + bv;
            }
        }
}

// ---------------------------------------------------------------------------
extern "C" void kernel_launch(void* const* d_in, const int* in_sizes, int n_in,
                              void* d_out, int out_size, void* d_ws, size_t ws_size,
                              hipStream_t stream)
{
    const float* x      = (const float*)d_in[0];
    const float* qkv_w  = (const float*)d_in[1];
    const float* proj_w = (const float*)d_in[2];
    const float* proj_b = (const float*)d_in[3];
    float* out = (float*)d_out;

    char* ws = (char*)d_ws;
    unsigned short* qd   = (unsigned short*)ws;                      //  4 MiB
    unsigned short* kd   = (unsigned short*)(ws + 4194304);          //  4 MiB
    unsigned short* vt   = (unsigned short*)(ws + 8388608);          //  4 MiB
    unsigned short* wqh  = (unsigned short*)(ws + 12582912);         // 1.5 MiB
    unsigned short* wql  = (unsigned short*)(ws + 14155776);         // 1.5 MiB
    unsigned short* wph  = (unsigned short*)(ws + 15728640);         // 0.5 MiB
    unsigned short* wpl  = (unsigned short*)(ws + 16252928);         // 0.5 MiB
    unsigned short* Oh   = (unsigned short*)(ws + 16777216);         //  4 MiB
    unsigned short* Ol   = (unsigned short*)(ws + 20971520);         //  4 MiB (end 24 MiB)

    prep<<<256, 256, 0, stream>>>(qkv_w, proj_w, wqh, wql, wph, wpl);
    gemm_qkv<<<dim3(24, 32), 256, 0, stream>>>(x, wqh, wql, qd, kd, vt);
    attn<<<512, 512, 0, stream>>>(qd, kd, vt, Oh, Ol);
    gemm_proj<<<dim3(8, 64), 256, 0, stream>>>(Oh, Ol, wph, wpl, proj_b, out);
}

// Round 9
// 149.916 us; speedup vs baseline: 1.1556x; 1.1556x over previous
//
#include <hip/hip_runtime.h>
#include <math.h>

constexpr int Bb = 2;
constexpr int Nn = 2048;
constexpr int Cc = 512;
constexpr int Hh = 8;
constexpr int Dd = 64;

typedef short short8 __attribute__((ext_vector_type(8)));
typedef float floatx4 __attribute__((ext_vector_type(4)));
typedef float floatx16 __attribute__((ext_vector_type(16)));

__device__ inline short8 bcs8(uint4 u) { return __builtin_bit_cast(short8, u); }
__device__ inline float4 bcf4(uint4 u) { return __builtin_bit_cast(float4, u); }

__device__ inline floatx4 mfma16(short8 a, short8 b, floatx4 c) {
    return __builtin_amdgcn_mfma_f32_16x16x32_bf16(a, b, c, 0, 0, 0);
}
__device__ inline floatx16 mfma32(short8 a, short8 b, floatx16 c) {
    return __builtin_amdgcn_mfma_f32_32x32x16_bf16(a, b, c, 0, 0, 0);
}

// async global->LDS, 16B per lane, dest = uniform base + lane*16
typedef __attribute__((address_space(1))) void gvoid;
typedef __attribute__((address_space(3))) void svoid;
__device__ inline void glds16(const void* g, void* l) {
    __builtin_amdgcn_global_load_lds((const gvoid*)g, (svoid*)l, 16, 0, 0);
}

#if __has_builtin(__builtin_amdgcn_exp2f)
#define EXP2(x) __builtin_amdgcn_exp2f(x)
#else
#define EXP2(x) __expf((x) * 0.69314718056f)
#endif

// pack bf16(a)|bf16(b)<<16, truncation (hi/lo splits: lo compensates hi)
__device__ inline unsigned pk_trunc(float a, float b) {
    return __builtin_amdgcn_perm(__float_as_uint(b), __float_as_uint(a), 0x07060302u);
}
// RNE pack
__device__ inline unsigned pk_rne(float a, float b) {
    unsigned ua = __float_as_uint(a); ua += 0x7fffu + ((ua >> 16) & 1u);
    unsigned ub = __float_as_uint(b); ub += 0x7fffu + ((ub >> 16) & 1u);
    return __builtin_amdgcn_perm(ub, ua, 0x07060302u);
}
__device__ inline unsigned short rne1(float a) {
    unsigned u = __float_as_uint(a); u += 0x7fffu + ((u >> 16) & 1u);
    return (unsigned short)(u >> 16);
}
__device__ inline float tr16(float a) {
    return __uint_as_float(__float_as_uint(a) & 0xffff0000u);
}
__device__ inline void split8(float4 A, float4 B, uint4& hi, uint4& lo) {
    hi = make_uint4(pk_trunc(A.x, A.y), pk_trunc(A.z, A.w),
                    pk_trunc(B.x, B.y), pk_trunc(B.z, B.w));
    lo = make_uint4(pk_trunc(A.x - tr16(A.x), A.y - tr16(A.y)),
                    pk_trunc(A.z - tr16(A.z), A.w - tr16(A.w)),
                    pk_trunc(B.x - tr16(B.x), B.y - tr16(B.y)),
                    pk_trunc(B.z - tr16(B.z), B.w - tr16(B.w)));
}

// ---------------------------------------------------------------------------
// prep: weight transpose + hi/lo split. grid 256 x 256thr.
// ---------------------------------------------------------------------------
__global__ __launch_bounds__(256) void prep(const float* __restrict__ qkv_w,
                                            const float* __restrict__ proj_w,
                                            unsigned short* __restrict__ wqh,
                                            unsigned short* __restrict__ wql,
                                            unsigned short* __restrict__ wph,
                                            unsigned short* __restrict__ wpl)
{
    __shared__ float Tl[64][68];
    int bid = blockIdx.x;
    const float* src; unsigned short *dh, *dlo; int W, f0, k0;
    if (bid < 192) { int kt = bid / 24, ft = bid % 24; W = 1536; src = qkv_w; dh = wqh; dlo = wql; f0 = ft * 64; k0 = kt * 64; }
    else { int b2 = bid - 192; int kt = b2 / 8, ft = b2 % 8; W = 512; src = proj_w; dh = wph; dlo = wpl; f0 = ft * 64; k0 = kt * 64; }
    int t = threadIdx.x;
    {
        int kl = t >> 2, fc = (t & 3) * 16;
        const float* p = src + (size_t)(k0 + kl) * W + f0 + fc;
        #pragma unroll
        for (int i = 0; i < 4; ++i) {
            float4 v = *(const float4*)(p + i * 4);
            Tl[kl][fc + i * 4 + 0] = v.x; Tl[kl][fc + i * 4 + 1] = v.y;
            Tl[kl][fc + i * 4 + 2] = v.z; Tl[kl][fc + i * 4 + 3] = v.w;
        }
    }
    __syncthreads();
    {
        int fl = t >> 2, kc = (t & 3) * 16;
        float v[16];
        #pragma unroll
        for (int i = 0; i < 16; ++i) v[i] = Tl[kc + i][fl];
        unsigned hi[8], lo[8];
        #pragma unroll
        for (int i = 0; i < 8; ++i) {
            float a = v[2 * i], b = v[2 * i + 1];
            hi[i] = pk_trunc(a, b);
            lo[i] = pk_trunc(a - tr16(a), b - tr16(b));
        }
        unsigned short* oh = dh + (size_t)(f0 + fl) * 512 + k0 + kc;
        unsigned short* ol = dlo + (size_t)(f0 + fl) * 512 + k0 + kc;
        *(uint4*)oh = make_uint4(hi[0], hi[1], hi[2], hi[3]);
        *(uint4*)(oh + 8) = make_uint4(hi[4], hi[5], hi[6], hi[7]);
        *(uint4*)ol = make_uint4(lo[0], lo[1], lo[2], lo[3]);
        *(uint4*)(ol + 8) = make_uint4(lo[4], lo[5], lo[6], lo[7]);
    }
}

// ---------------------------------------------------------------------------
// GEMM1: x(fp32, staged+split in-kernel) @ qkv_w(split,T).
// Outputs: qd[bh][n][64] row-major (pre-scaled by 0.125*log2e);
//   kfrag: MFMA A-operand fragment-major — frag(bh*64+kb, s) 1KB: lane l ->
//     K[key kb*32+(l&31)][d s*16+(l>>5)*8+j]  (written via 2B scatter);
//   vfrag: frag(bh*128+j, mtv) 1KB: lane l ->
//     V^T[d mtv*32+(l&31)][key j*16+(l>>5)*8+j2]  (dense uint2 stores).
// BM=128 BN=64, pipelined BK=32 stages (2 x 24 KB LDS), 256 thr, grid (24,32).
// ---------------------------------------------------------------------------
__global__ __launch_bounds__(256, 3) void gemm_qkv(const float* __restrict__ x,
                                                   const unsigned short* __restrict__ wh,
                                                   const unsigned short* __restrict__ wl,
                                                   unsigned short* __restrict__ qd,
                                                   unsigned short* __restrict__ kfrag,
                                                   unsigned short* __restrict__ vfrag)
{
    __shared__ __align__(16) char smem[49152];   // 2 x [A 16K | Bh 4K | Bl 4K]
    const int tid = threadIdx.x, lane = tid & 63, w = tid >> 6;
    const int l15 = lane & 15, l4 = lane >> 4;
    const int row0 = blockIdx.y * 128, col0 = blockIdx.x * 64;
    const int wm = w >> 1, wn = w & 1;

    floatx4 acc[4][2];
    #pragma unroll
    for (int i = 0; i < 4; ++i)
        #pragma unroll
        for (int j = 0; j < 2; ++j)
            #pragma unroll
            for (int r = 0; r < 4; ++r) acc[i][j][r] = 0.f;

    auto stage = [&](int k0, char* buf) {
        #pragma unroll
        for (int i = 0; i < 4; ++i) {            // A: 16 segs (mt8 x sub2), fp32
            int sid = w * 4 + i; int mt = sid >> 1, sub = sid & 1;
            const float* src = x + (size_t)(row0 + mt * 16 + l15) * 512 + k0 + l4 * 8 + sub * 4;
            glds16(src, buf + sid * 1024);
        }
        #pragma unroll
        for (int i = 0; i < 2; ++i) {            // B: 8 segs (4 nt x hi/lo)
            int sid = w * 2 + i; int nt = sid >> 1, comp = sid & 1;
            const unsigned short* src = (comp ? wl : wh) + (size_t)(col0 + nt * 16 + l15) * 512 + k0 + l4 * 8;
            glds16(src, buf + 16384 + comp * 4096 + nt * 1024);
        }
    };

    stage(0, smem);
    for (int it = 0; it < 16; ++it) {
        __syncthreads();                          // drains stage(it); prev readers done
        char* buf = smem + (it & 1) * 24576;
        if (it < 15) stage((it + 1) * 32, smem + ((it + 1) & 1) * 24576);
        char* Ab = buf; char* Bh = buf + 16384; char* Bl = buf + 20480;
        short8 af[4][2], bf[2][2];
        #pragma unroll
        for (int mt = 0; mt < 4; ++mt) {
            int off = (((wm * 4 + mt) * 2) << 10) + (lane << 4);
            float4 fa = bcf4(*(const uint4*)(Ab + off));
            float4 fb = bcf4(*(const uint4*)(Ab + off + 1024));
            uint4 hi, lo;
            split8(fa, fb, hi, lo);
            af[mt][0] = bcs8(hi);
            af[mt][1] = bcs8(lo);
        }
        #pragma unroll
        for (int nt = 0; nt < 2; ++nt) {
            int off = ((wn * 2 + nt) << 10) + (lane << 4);
            bf[nt][0] = bcs8(*(const uint4*)(Bh + off));
            bf[nt][1] = bcs8(*(const uint4*)(Bl + off));
        }
        #pragma unroll
        for (int mt = 0; mt < 4; ++mt)
            #pragma unroll
            for (int nt = 0; nt < 2; ++nt) {
                acc[mt][nt] = mfma16(af[mt][0], bf[nt][0], acc[mt][nt]);
                acc[mt][nt] = mfma16(af[mt][0], bf[nt][1], acc[mt][nt]);
                acc[mt][nt] = mfma16(af[mt][1], bf[nt][0], acc[mt][nt]);
            }
    }
    // epilogue: q row-major (scaled); K scatter to kfrag; V dense to vfrag.
    #pragma unroll
    for (int mt = 0; mt < 4; ++mt)
        #pragma unroll
        for (int nt = 0; nt < 2; ++nt) {
            int c = col0 + (wn * 2 + nt) * 16 + l15;     // 0..1535
            int which = c >> 9;                          // 0=q,1=k,2=v (block-uniform)
            int head = (c >> 6) & 7, d = c & 63;
            int tokb = row0 + (wm * 4 + mt) * 16 + l4 * 4;
            int b = tokb >> 11, n = tokb & 2047;
            int bh = b * 8 + head;
            if (which == 0) {
                #pragma unroll
                for (int r = 0; r < 4; ++r)
                    qd[(size_t)(bh * 2048 + n + r) * 64 + d] = rne1(acc[mt][nt][r] * 0.18033688f);
            } else if (which == 1) {
                int s = d >> 4;
                size_t fb_ = ((size_t)(bh * 64 + (n >> 5)) * 4 + s) * 512 + (d & 7);
                int hl = ((d >> 3) & 1) * 32;
                #pragma unroll
                for (int r = 0; r < 4; ++r)
                    kfrag[fb_ + (size_t)(hl + ((n + r) & 31)) * 8] = rne1(acc[mt][nt][r]);
            } else {
                int j = n >> 4, mtv = d >> 5;
                uint2 pv;
                pv.x = pk_rne(acc[mt][nt][0], acc[mt][nt][1]);
                pv.y = pk_rne(acc[mt][nt][2], acc[mt][nt][3]);
                *(uint2*)&vfrag[((size_t)(bh * 128 + j) * 2 + mtv) * 512 +
                                (size_t)(((n >> 3) & 1) * 32 + (d & 31)) * 8 + (n & 7)] = pv;
            }
        }
}

// ---------------------------------------------------------------------------
// Attention: NO in-loop LDS, NO in-loop barriers. Grid 1024 = 16 bh x 64
// qtiles (32 q), XCD-swizzled. 256 thr = 4 independent waves; wave kg owns
// the contiguous 512-key strip [kg*512, +512), 16 steps of 32 keys. All K/V
// fragment loads are dense 1 KB (lane*16) from fragment-major kfrag/vfrag —
// the compiler pipelines them across the unrolled loop with fine vmcnt.
// S^T = K.Q^T (mfma32, log2e folded into Q -> raw exp2); P trunc-packed;
// l via all-ones-A MFMA; P transform = 2 shuffles/kc. LDS merge at end only.
// ---------------------------------------------------------------------------
__global__ __launch_bounds__(256, 4) void attn(const unsigned short* __restrict__ qd,
                                               const unsigned short* __restrict__ kfrag,
                                               const unsigned short* __restrict__ vfrag,
                                               unsigned short* __restrict__ Oh,
                                               unsigned short* __restrict__ Ol)
{
    __shared__ float Ms[2048];     // [d(64)][q(32)]
    __shared__ float Ls[64];       // [h(2)][q(32)] (dup halves)
    __shared__ float Ts[2176];     // [q(32)][68]

    int bid = blockIdx.x;
    int xcd = bid & 7; int rr = bid >> 3;
    int qt = rr & 63; int bhi = rr >> 6;
    int bh = (bhi << 3) | xcd;
    int tid = threadIdx.x, lane = tid & 63, kg = tid >> 6;
    int l31 = lane & 31, h = lane >> 5;

    // Q^T fragments (B-operand), once (pre-scaled, log2e folded)
    short8 qf[4];
    #pragma unroll
    for (int s = 0; s < 4; ++s)
        qf[s] = bcs8(*(const uint4*)(qd + ((size_t)bh * 2048 + qt * 32 + l31) * 64 + s * 16 + h * 8));

    const uint4 onesu = make_uint4(0x3F803F80u, 0x3F803F80u, 0x3F803F80u, 0x3F803F80u);
    const short8 onesf = bcs8(onesu);

    floatx16 OT[2], OTl;
    #pragma unroll
    for (int i = 0; i < 2; ++i)
        #pragma unroll
        for (int r = 0; r < 16; ++r) OT[i][r] = 0.f;
    #pragma unroll
    for (int r = 0; r < 16; ++r) OTl[r] = 0.f;

    // dense fragment bases (shorts)
    const unsigned short* kb_ = kfrag + ((size_t)(bh * 64 + kg * 16) * 4) * 512 + lane * 8;
    const unsigned short* vb_ = vfrag + ((size_t)(bh * 128 + kg * 32) * 2) * 512 + lane * 8;

    #pragma unroll
    for (int c = 0; c < 16; ++c) {
        uint4 kfu[4];
        #pragma unroll
        for (int s = 0; s < 4; ++s)
            kfu[s] = *(const uint4*)(kb_ + ((size_t)c * 4 + s) * 512);
        uint4 vfu[2][2];
        #pragma unroll
        for (int kc = 0; kc < 2; ++kc)
            #pragma unroll
            for (int mtv = 0; mtv < 2; ++mtv)
                vfu[kc][mtv] = *(const uint4*)(vb_ + ((size_t)(c * 2 + kc) * 2 + mtv) * 512);

        floatx16 st;
        #pragma unroll
        for (int r = 0; r < 16; ++r) st[r] = 0.f;
        #pragma unroll
        for (int s = 0; s < 4; ++s) st = mfma32(bcs8(kfu[s]), qf[s], st);

        // exp2 (log2e pre-folded), truncation pack (bias cancels via MFMA-l)
        unsigned P2[8];
        #pragma unroll
        for (int s2 = 0; s2 < 8; ++s2)
            P2[s2] = pk_trunc(EXP2(st[2 * s2]), EXP2(st[2 * s2 + 1]));

        #pragma unroll
        for (int kc = 0; kc < 2; ++kc) {
            unsigned X0 = P2[4 * kc + 0], X1 = P2[4 * kc + 1];
            unsigned Y0 = P2[4 * kc + 2], Y1 = P2[4 * kc + 3];
            unsigned T0 = h ? X0 : Y0;
            unsigned T1 = h ? X1 : Y1;
            unsigned To0 = __shfl_xor(T0, 32, 64);
            unsigned To1 = __shfl_xor(T1, 32, 64);
            uint4 fu;
            fu.x = h ? To0 : X0;
            fu.y = h ? To1 : X1;
            fu.z = h ? Y0 : To0;
            fu.w = h ? Y1 : To1;
            short8 pf = bcs8(fu);
            OT[0] = mfma32(bcs8(vfu[kc][0]), pf, OT[0]);
            OT[1] = mfma32(bcs8(vfu[kc][1]), pf, OT[1]);
            OTl = mfma32(onesf, pf, OTl);         // l += column-sums of rounded P
        }
    }

    // ---- merge partial O/l across the 4 kg waves ----
    if (kg == 3) {
        #pragma unroll
        for (int mtv = 0; mtv < 2; ++mtv)
            #pragma unroll
            for (int r = 0; r < 16; ++r) {
                int d = mtv * 32 + (r & 3) + 8 * (r >> 2) + 4 * h;
                Ms[d * 32 + l31] = OT[mtv][r];
            }
        Ls[h * 32 + l31] = OTl[0];
    }
    __syncthreads();
    if (kg == 2) {
        #pragma unroll
        for (int mtv = 0; mtv < 2; ++mtv)
            #pragma unroll
            for (int r = 0; r < 16; ++r) {
                int d = mtv * 32 + (r & 3) + 8 * (r >> 2) + 4 * h;
                Ms[d * 32 + l31] += OT[mtv][r];
            }
        Ls[h * 32 + l31] += OTl[0];
    }
    __syncthreads();
    if (kg == 1) {
        #pragma unroll
        for (int mtv = 0; mtv < 2; ++mtv)
            #pragma unroll
            for (int r = 0; r < 16; ++r) {
                int d = mtv * 32 + (r & 3) + 8 * (r >> 2) + 4 * h;
                Ms[d * 32 + l31] += OT[mtv][r];
            }
        Ls[h * 32 + l31] += OTl[0];
    }
    __syncthreads();
    if (kg == 0) {
        #pragma unroll
        for (int mtv = 0; mtv < 2; ++mtv)
            #pragma unroll
            for (int r = 0; r < 16; ++r) {
                int d = mtv * 32 + (r & 3) + 8 * (r >> 2) + 4 * h;
                OT[mtv][r] += Ms[d * 32 + l31];
            }
        float inv = 1.f / (Ls[h * 32 + l31] + OTl[0]);      // halves are duplicates
        #pragma unroll
        for (int mtv = 0; mtv < 2; ++mtv)
            #pragma unroll
            for (int r = 0; r < 16; ++r) {
                int d = mtv * 32 + (r & 3) + 8 * (r >> 2) + 4 * h;
                Ts[l31 * 68 + d] = OT[mtv][r] * inv;
            }
    }
    __syncthreads();
    // all 256 threads: coalesced split-bf16 store of O (flat B,H,N,D)
    {
        int q = tid >> 3, dc = (tid & 7) * 8;               // q 0..31
        float vv[8];
        #pragma unroll
        for (int i = 0; i < 8; ++i) vv[i] = Ts[q * 68 + dc + i];
        unsigned hi[4], lo[4];
        #pragma unroll
        for (int i = 0; i < 4; ++i) {
            float a = vv[2 * i], bb = vv[2 * i + 1];
            hi[i] = pk_trunc(a, bb);
            lo[i] = pk_trunc(a - tr16(a), bb - tr16(bb));
        }
        size_t bo = ((size_t)(bh * 2048 + qt * 32 + q)) * 64 + dc;
        *(uint4*)(Oh + bo) = make_uint4(hi[0], hi[1], hi[2], hi[3]);
        *(uint4*)(Ol + bo) = make_uint4(lo[0], lo[1], lo[2], lo[3]);
    }
}

// ---------------------------------------------------------------------------
// GEMM2: out = O(split) @ proj_w(split,T) + bias. BM=64 BN=64, pipelined
// BK=32 stages (2 x 16 KB LDS). 256 thr = 4 waves of 32x32. grid (8,64).
// ---------------------------------------------------------------------------
__global__ __launch_bounds__(256, 2) void gemm_proj(const unsigned short* __restrict__ Ah_g,
                                                    const unsigned short* __restrict__ Al_g,
                                                    const unsigned short* __restrict__ wh,
                                                    const unsigned short* __restrict__ wl,
                                                    const float* __restrict__ bias,
                                                    float* __restrict__ out)
{
    __shared__ __align__(16) char smem[32768];   // 2 x [Ah 4K | Al 4K | Bh 4K | Bl 4K]
    const int tid = threadIdx.x, lane = tid & 63, w = tid >> 6;
    const int l15 = lane & 15, l4 = lane >> 4;
    const int row0 = blockIdx.y * 64, col0 = blockIdx.x * 64;
    const int wm = w >> 1, wn = w & 1;

    floatx4 acc[2][2];
    #pragma unroll
    for (int i = 0; i < 2; ++i)
        #pragma unroll
        for (int j = 0; j < 2; ++j)
            #pragma unroll
            for (int r = 0; r < 4; ++r) acc[i][j][r] = 0.f;

    auto stage = [&](int k0, char* buf) {
        #pragma unroll
        for (int i = 0; i < 4; ++i) {            // 16 segs: 8 A + 8 B
            int sid = w * 4 + i;
            if (sid < 8) {
                int mt = sid >> 1, comp = sid & 1;
                const unsigned short* src = (comp ? Al_g : Ah_g) + (size_t)(row0 + mt * 16 + l15) * 512 + k0 + l4 * 8;
                glds16(src, buf + (comp ? 4096 : 0) + mt * 1024);
            } else {
                int s2 = sid - 8; int nt = s2 >> 1, comp = s2 & 1;
                const unsigned short* src = (comp ? wl : wh) + (size_t)(col0 + nt * 16 + l15) * 512 + k0 + l4 * 8;
                glds16(src, buf + (comp ? 12288 : 8192) + nt * 1024);
            }
        }
    };

    stage(0, smem);
    for (int it = 0; it < 16; ++it) {
        __syncthreads();
        char* buf = smem + (it & 1) * 16384;
        if (it < 15) stage((it + 1) * 32, smem + ((it + 1) & 1) * 16384);
        char* Ah = buf; char* Al = buf + 4096; char* Bh = buf + 8192; char* Bl = buf + 12288;
        short8 af[2][2], bf[2][2];
        #pragma unroll
        for (int mt = 0; mt < 2; ++mt) {
            int off = ((wm * 2 + mt) << 10) + (lane << 4);
            af[mt][0] = bcs8(*(const uint4*)(Ah + off));
            af[mt][1] = bcs8(*(const uint4*)(Al + off));
        }
        #pragma unroll
        for (int nt = 0; nt < 2; ++nt) {
            int off = ((wn * 2 + nt) << 10) + (lane << 4);
            bf[nt][0] = bcs8(*(const uint4*)(Bh + off));
            bf[nt][1] = bcs8(*(const uint4*)(Bl + off));
        }
        #pragma unroll
        for (int mt = 0; mt < 2; ++mt)
            #pragma unroll
            for (int nt = 0; nt < 2; ++nt) {
                acc[mt][nt] = mfma16(af[mt][0], bf[nt][0], acc[mt][nt]);
                acc[mt][nt] = mfma16(af[mt][0], bf[nt][1], acc[mt][nt]);
                acc[mt][nt] = mfma16(af[mt][1], bf[nt][0], acc[mt][nt]);
            }
    }
    #pragma unroll
    for (int mt = 0; mt < 2; ++mt)
        #pragma unroll
        for (int nt = 0; nt < 2; ++nt) {
            int c = col0 + (wn * 2 + nt) * 16 + l15;
            float bv = bias[c];
            #pragma unroll
            for (int r = 0; r < 4; ++r) {
                int tok = row0 + (wm * 2 + mt) * 16 + l4 * 4 + r;
                out[(size_t)tok * 512 + c] = acc[mt][nt][r] + bv;
            }
        }
}

// ---------------------------------------------------------------------------
extern "C" void kernel_launch(void* const* d_in, const int* in_sizes, int n_in,
                              void* d_out, int out_size, void* d_ws, size_t ws_size,
                              hipStream_t stream)
{
    const float* x      = (const float*)d_in[0];
    const float* qkv_w  = (const float*)d_in[1];
    const float* proj_w = (const float*)d_in[2];
    const float* proj_b = (const float*)d_in[3];
    float* out = (float*)d_out;

    char* ws = (char*)d_ws;
    unsigned short* qd    = (unsigned short*)ws;                      //  4 MiB
    unsigned short* kfrag = (unsigned short*)(ws + 4194304);          //  4 MiB
    unsigned short* vfrag = (unsigned short*)(ws + 8388608);          //  4 MiB
    unsigned short* wqh   = (unsigned short*)(ws + 12582912);         // 1.5 MiB
    unsigned short* wql   = (unsigned short*)(ws + 14155776);         // 1.5 MiB
    unsigned short* wph   = (unsigned short*)(ws + 15728640);         // 0.5 MiB
    unsigned short* wpl   = (unsigned short*)(ws + 16252928);         // 0.5 MiB
    unsigned short* Oh    = (unsigned short*)(ws + 16777216);         //  4 MiB
    unsigned short* Ol    = (unsigned short*)(ws + 20971520);         //  4 MiB (end 24 MiB)

    prep<<<256, 256, 0, stream>>>(qkv_w, proj_w, wqh, wql, wph, wpl);
    gemm_qkv<<<dim3(24, 32), 256, 0, stream>>>(x, wqh, wql, qd, kfrag, vfrag);
    attn<<<1024, 256, 0, stream>>>(qd, kfrag, vfrag, Oh, Ol);
    gemm_proj<<<dim3(8, 64), 256, 0, stream>>>(Oh, Ol, wph, wpl, proj_b, out);
}

// Round 10
// 139.853 us; speedup vs baseline: 1.2387x; 1.0720x over previous
//
#include <hip/hip_runtime.h>
#include <math.h>

constexpr int Bb = 2;
constexpr int Nn = 2048;
constexpr int Cc = 512;
constexpr int Hh = 8;
constexpr int Dd = 64;

typedef short short8 __attribute__((ext_vector_type(8)));
typedef float floatx4 __attribute__((ext_vector_type(4)));
typedef float floatx16 __attribute__((ext_vector_type(16)));

__device__ inline short8 bcs8(uint4 u) { return __builtin_bit_cast(short8, u); }

__device__ inline floatx4 mfma16(short8 a, short8 b, floatx4 c) {
    return __builtin_amdgcn_mfma_f32_16x16x32_bf16(a, b, c, 0, 0, 0);
}
__device__ inline floatx16 mfma32(short8 a, short8 b, floatx16 c) {
    return __builtin_amdgcn_mfma_f32_32x32x16_bf16(a, b, c, 0, 0, 0);
}

#if __has_builtin(__builtin_amdgcn_exp2f)
#define EXP2(x) __builtin_amdgcn_exp2f(x)
#else
#define EXP2(x) __expf((x) * 0.69314718056f)
#endif

// pack bf16(a)|bf16(b)<<16, truncation (hi/lo splits: lo compensates hi)
__device__ inline unsigned pk_trunc(float a, float b) {
    return __builtin_amdgcn_perm(__float_as_uint(b), __float_as_uint(a), 0x07060302u);
}
// RNE pack
__device__ inline unsigned pk_rne(float a, float b) {
    unsigned ua = __float_as_uint(a); ua += 0x7fffu + ((ua >> 16) & 1u);
    unsigned ub = __float_as_uint(b); ub += 0x7fffu + ((ub >> 16) & 1u);
    return __builtin_amdgcn_perm(ub, ua, 0x07060302u);
}
__device__ inline unsigned short rne1(float a) {
    unsigned u = __float_as_uint(a); u += 0x7fffu + ((u >> 16) & 1u);
    return (unsigned short)(u >> 16);
}
__device__ inline float tr16(float a) {
    return __uint_as_float(__float_as_uint(a) & 0xffff0000u);
}
__device__ inline void split8(float4 A, float4 B, uint4& hi, uint4& lo) {
    hi = make_uint4(pk_trunc(A.x, A.y), pk_trunc(A.z, A.w),
                    pk_trunc(B.x, B.y), pk_trunc(B.z, B.w));
    lo = make_uint4(pk_trunc(A.x - tr16(A.x), A.y - tr16(A.y)),
                    pk_trunc(A.z - tr16(A.z), A.w - tr16(A.w)),
                    pk_trunc(B.x - tr16(B.x), B.y - tr16(B.y)),
                    pk_trunc(B.z - tr16(B.z), B.w - tr16(B.w)));
}

// Fragment-major layout (16x16x32 MFMA operand):
//   frag(idx, kc, comp): 1 KB at (((idx*16 + kc)*2 + comp) * 512) shorts;
//   lane l holds elem[row l&15][k kc*32 + (l>>4)*8 + jj], 8 bf16 = 16 B.

// ---------------------------------------------------------------------------
// prep: bid<256 -> weights transpose+split -> B-frag-major wqfrag/wpfrag;
//       bid>=256 -> x split -> A-frag-major xfrag (hi/lo).
// ---------------------------------------------------------------------------
__global__ __launch_bounds__(256) void prep(const float* __restrict__ qkv_w,
                                            const float* __restrict__ proj_w,
                                            const float* __restrict__ x,
                                            unsigned short* __restrict__ wqfrag,
                                            unsigned short* __restrict__ wpfrag,
                                            unsigned short* __restrict__ xfrag)
{
    __shared__ float Tl[64][68];
    int bid = blockIdx.x;
    int t = threadIdx.x;
    if (bid >= 256) {                      // ---- x -> A-frag split ----
        int xb = bid - 256;                // 0..255
        int tok = xb * 16 + (t >> 4);      // 16 tokens/block
        int kc = t & 15;                   // k-chunk of 32
        const float* px = x + (size_t)tok * 512 + kc * 32;
        uint4 h[4], l[4];
        #pragma unroll
        for (int o = 0; o < 4; ++o) {
            float4 fa = *(const float4*)(px + o * 8);
            float4 fb = *(const float4*)(px + o * 8 + 4);
            split8(fa, fb, h[o], l[o]);
        }
        int mt = tok >> 4, m = tok & 15;
        unsigned short* fb_ = xfrag + ((size_t)(mt * 16 + kc) * 2) * 512;
        #pragma unroll
        for (int o = 0; o < 4; ++o) {
            *(uint4*)(fb_ + (m + 16 * o) * 8) = h[o];
            *(uint4*)(fb_ + 512 + (m + 16 * o) * 8) = l[o];
        }
        return;
    }
    // ---- weight transpose + split -> B-frag-major ----
    const float* src; unsigned short* dfrag; int W, f0, k0;
    if (bid < 192) { int kt = bid / 24, ft = bid % 24; W = 1536; src = qkv_w; dfrag = wqfrag; f0 = ft * 64; k0 = kt * 64; }
    else { int b2 = bid - 192; int kt = b2 / 8, ft = b2 % 8; W = 512; src = proj_w; dfrag = wpfrag; f0 = ft * 64; k0 = kt * 64; }
    {
        int kl = t >> 2, fc = (t & 3) * 16;
        const float* p = src + (size_t)(k0 + kl) * W + f0 + fc;
        #pragma unroll
        for (int i = 0; i < 4; ++i) {
            float4 v = *(const float4*)(p + i * 4);
            Tl[kl][fc + i * 4 + 0] = v.x; Tl[kl][fc + i * 4 + 1] = v.y;
            Tl[kl][fc + i * 4 + 2] = v.z; Tl[kl][fc + i * 4 + 3] = v.w;
        }
    }
    __syncthreads();
    {
        int fl = t >> 2, kc16 = (t & 3) * 16;
        float v[16];
        #pragma unroll
        for (int i = 0; i < 16; ++i) v[i] = Tl[kc16 + i][fl];
        unsigned hi[8], lo[8];
        #pragma unroll
        for (int i = 0; i < 8; ++i) {
            float a = v[2 * i], b = v[2 * i + 1];
            hi[i] = pk_trunc(a, b);
            lo[i] = pk_trunc(a - tr16(a), b - tr16(b));
        }
        int f = f0 + fl;
        int nt = f >> 4, nin = f & 15;
        int kc = (k0 + kc16) >> 5;
        int oct0 = (kc16 >> 3) & 3;        // 0 or 2
        unsigned short* fb_ = dfrag + ((size_t)(nt * 16 + kc) * 2) * 512;
        *(uint4*)(fb_ + (nin + 16 * oct0) * 8) = make_uint4(hi[0], hi[1], hi[2], hi[3]);
        *(uint4*)(fb_ + (nin + 16 * (oct0 + 1)) * 8) = make_uint4(hi[4], hi[5], hi[6], hi[7]);
        *(uint4*)(fb_ + 512 + (nin + 16 * oct0) * 8) = make_uint4(lo[0], lo[1], lo[2], lo[3]);
        *(uint4*)(fb_ + 512 + (nin + 16 * (oct0 + 1)) * 8) = make_uint4(lo[4], lo[5], lo[6], lo[7]);
    }
}

// ---------------------------------------------------------------------------
// GEMM1: barrier-free, zero-LDS. Block = 64 tok x 128 cols; 4 waves, each
// 4 mt x 2 nt of 16x16x32 split-bf16 MFMA streaming dense fragments.
// grid (12, 64). Outputs: qd row-major (pre-scaled 0.125*log2e), kfrag
// (32x32x16 A-op frag-major), vfrag (PV A-op frag-major) — as round 9.
// ---------------------------------------------------------------------------
__global__ __launch_bounds__(256, 4) void gemm_qkv(const unsigned short* __restrict__ xfrag,
                                                   const unsigned short* __restrict__ wqfrag,
                                                   unsigned short* __restrict__ qd,
                                                   unsigned short* __restrict__ kfrag,
                                                   unsigned short* __restrict__ vfrag)
{
    const int tid = threadIdx.x, lane = tid & 63, w = tid >> 6;
    const int l15 = lane & 15, l4 = lane >> 4;
    const int row0 = blockIdx.y * 64, col0 = blockIdx.x * 128;
    const int mt0 = row0 >> 4;             // 4 consecutive mt
    const int nt0 = (col0 >> 4) + w * 2;   // 2 consecutive nt per wave

    floatx4 acc[4][2];
    #pragma unroll
    for (int i = 0; i < 4; ++i)
        #pragma unroll
        for (int j = 0; j < 2; ++j)
            #pragma unroll
            for (int r = 0; r < 4; ++r) acc[i][j][r] = 0.f;

    const unsigned short* xb = xfrag + (size_t)lane * 8;
    const unsigned short* wb = wqfrag + (size_t)lane * 8;

    #pragma unroll
    for (int kc = 0; kc < 16; ++kc) {
        short8 bf[2][2];
        #pragma unroll
        for (int nt = 0; nt < 2; ++nt) {
            size_t fb_ = ((size_t)((nt0 + nt) * 16 + kc) * 2) * 512;
            bf[nt][0] = bcs8(*(const uint4*)(wb + fb_));
            bf[nt][1] = bcs8(*(const uint4*)(wb + fb_ + 512));
        }
        #pragma unroll
        for (int mt = 0; mt < 4; ++mt) {
            size_t fa_ = ((size_t)((mt0 + mt) * 16 + kc) * 2) * 512;
            short8 ah = bcs8(*(const uint4*)(xb + fa_));
            short8 al = bcs8(*(const uint4*)(xb + fa_ + 512));
            #pragma unroll
            for (int nt = 0; nt < 2; ++nt) {
                acc[mt][nt] = mfma16(ah, bf[nt][0], acc[mt][nt]);
                acc[mt][nt] = mfma16(ah, bf[nt][1], acc[mt][nt]);
                acc[mt][nt] = mfma16(al, bf[nt][0], acc[mt][nt]);
            }
        }
    }
    // epilogue: q row-major (scaled); K scatter to kfrag; V dense to vfrag.
    #pragma unroll
    for (int mt = 0; mt < 4; ++mt)
        #pragma unroll
        for (int nt = 0; nt < 2; ++nt) {
            int c = col0 + (w * 2 + nt) * 16 + l15;      // 0..1535
            int which = c >> 9;                          // 0=q,1=k,2=v (block-uniform)
            int head = (c >> 6) & 7, d = c & 63;
            int tokb = row0 + mt * 16 + l4 * 4;
            int b = tokb >> 11, n = tokb & 2047;
            int bh = b * 8 + head;
            if (which == 0) {
                #pragma unroll
                for (int r = 0; r < 4; ++r)
                    qd[(size_t)(bh * 2048 + n + r) * 64 + d] = rne1(acc[mt][nt][r] * 0.18033688f);
            } else if (which == 1) {
                int s = d >> 4;
                size_t fb_ = ((size_t)(bh * 64 + (n >> 5)) * 4 + s) * 512 + (d & 7);
                int hl = ((d >> 3) & 1) * 32;
                #pragma unroll
                for (int r = 0; r < 4; ++r)
                    kfrag[fb_ + (size_t)(hl + ((n + r) & 31)) * 8] = rne1(acc[mt][nt][r]);
            } else {
                int j = n >> 4, mtv = d >> 5;
                uint2 pv;
                pv.x = pk_rne(acc[mt][nt][0], acc[mt][nt][1]);
                pv.y = pk_rne(acc[mt][nt][2], acc[mt][nt][3]);
                *(uint2*)&vfrag[((size_t)(bh * 128 + j) * 2 + mtv) * 512 +
                                (size_t)(((n >> 3) & 1) * 32 + (d & 31)) * 8 + (n & 7)] = pv;
            }
        }
}

// ---------------------------------------------------------------------------
// Attention: round-9 structure (no in-loop LDS/barriers; 4 independent
// kg-waves on 512-key strips; dense fragment loads). Epilogue now writes O
// A-FRAGMENT-MAJOR (hi/lo) for the barrier-free gemm_proj, honoring the
// reference's buggy reshape: gemm2 row r = bh*256 + n/8, col c = (n%8)*64+d.
// ---------------------------------------------------------------------------
__global__ __launch_bounds__(256, 4) void attn(const unsigned short* __restrict__ qd,
                                               const unsigned short* __restrict__ kfrag,
                                               const unsigned short* __restrict__ vfrag,
                                               unsigned short* __restrict__ Ofrag)
{
    __shared__ float Ms[2048];     // [d(64)][q(32)]
    __shared__ float Ls[64];       // [h(2)][q(32)] (dup halves)
    __shared__ float Ts[2176];     // [q(32)][68]

    int bid = blockIdx.x;
    int xcd = bid & 7; int rr = bid >> 3;
    int qt = rr & 63; int bhi = rr >> 6;
    int bh = (bhi << 3) | xcd;
    int tid = threadIdx.x, lane = tid & 63, kg = tid >> 6;
    int l31 = lane & 31, h = lane >> 5;

    // Q^T fragments (B-operand), once (pre-scaled, log2e folded)
    short8 qf[4];
    #pragma unroll
    for (int s = 0; s < 4; ++s)
        qf[s] = bcs8(*(const uint4*)(qd + ((size_t)bh * 2048 + qt * 32 + l31) * 64 + s * 16 + h * 8));

    const uint4 onesu = make_uint4(0x3F803F80u, 0x3F803F80u, 0x3F803F80u, 0x3F803F80u);
    const short8 onesf = bcs8(onesu);

    floatx16 OT[2], OTl;
    #pragma unroll
    for (int i = 0; i < 2; ++i)
        #pragma unroll
        for (int r = 0; r < 16; ++r) OT[i][r] = 0.f;
    #pragma unroll
    for (int r = 0; r < 16; ++r) OTl[r] = 0.f;

    const unsigned short* kb_ = kfrag + ((size_t)(bh * 64 + kg * 16) * 4) * 512 + lane * 8;
    const unsigned short* vb_ = vfrag + ((size_t)(bh * 128 + kg * 32) * 2) * 512 + lane * 8;

    #pragma unroll
    for (int c = 0; c < 16; ++c) {
        uint4 kfu[4];
        #pragma unroll
        for (int s = 0; s < 4; ++s)
            kfu[s] = *(const uint4*)(kb_ + ((size_t)c * 4 + s) * 512);
        uint4 vfu[2][2];
        #pragma unroll
        for (int kc = 0; kc < 2; ++kc)
            #pragma unroll
            for (int mtv = 0; mtv < 2; ++mtv)
                vfu[kc][mtv] = *(const uint4*)(vb_ + ((size_t)(c * 2 + kc) * 2 + mtv) * 512);

        floatx16 st;
        #pragma unroll
        for (int r = 0; r < 16; ++r) st[r] = 0.f;
        #pragma unroll
        for (int s = 0; s < 4; ++s) st = mfma32(bcs8(kfu[s]), qf[s], st);

        unsigned P2[8];
        #pragma unroll
        for (int s2 = 0; s2 < 8; ++s2)
            P2[s2] = pk_trunc(EXP2(st[2 * s2]), EXP2(st[2 * s2 + 1]));

        #pragma unroll
        for (int kc = 0; kc < 2; ++kc) {
            unsigned X0 = P2[4 * kc + 0], X1 = P2[4 * kc + 1];
            unsigned Y0 = P2[4 * kc + 2], Y1 = P2[4 * kc + 3];
            unsigned T0 = h ? X0 : Y0;
            unsigned T1 = h ? X1 : Y1;
            unsigned To0 = __shfl_xor(T0, 32, 64);
            unsigned To1 = __shfl_xor(T1, 32, 64);
            uint4 fu;
            fu.x = h ? To0 : X0;
            fu.y = h ? To1 : X1;
            fu.z = h ? Y0 : To0;
            fu.w = h ? Y1 : To1;
            short8 pf = bcs8(fu);
            OT[0] = mfma32(bcs8(vfu[kc][0]), pf, OT[0]);
            OT[1] = mfma32(bcs8(vfu[kc][1]), pf, OT[1]);
            OTl = mfma32(onesf, pf, OTl);         // l += column-sums of rounded P
        }
    }

    // ---- merge partial O/l across the 4 kg waves ----
    if (kg == 3) {
        #pragma unroll
        for (int mtv = 0; mtv < 2; ++mtv)
            #pragma unroll
            for (int r = 0; r < 16; ++r) {
                int d = mtv * 32 + (r & 3) + 8 * (r >> 2) + 4 * h;
                Ms[d * 32 + l31] = OT[mtv][r];
            }
        Ls[h * 32 + l31] = OTl[0];
    }
    __syncthreads();
    if (kg == 2) {
        #pragma unroll
        for (int mtv = 0; mtv < 2; ++mtv)
            #pragma unroll
            for (int r = 0; r < 16; ++r) {
                int d = mtv * 32 + (r & 3) + 8 * (r >> 2) + 4 * h;
                Ms[d * 32 + l31] += OT[mtv][r];
            }
        Ls[h * 32 + l31] += OTl[0];
    }
    __syncthreads();
    if (kg == 1) {
        #pragma unroll
        for (int mtv = 0; mtv < 2; ++mtv)
            #pragma unroll
            for (int r = 0; r < 16; ++r) {
                int d = mtv * 32 + (r & 3) + 8 * (r >> 2) + 4 * h;
                Ms[d * 32 + l31] += OT[mtv][r];
            }
        Ls[h * 32 + l31] += OTl[0];
    }
    __syncthreads();
    if (kg == 0) {
        #pragma unroll
        for (int mtv = 0; mtv < 2; ++mtv)
            #pragma unroll
            for (int r = 0; r < 16; ++r) {
                int d = mtv * 32 + (r & 3) + 8 * (r >> 2) + 4 * h;
                OT[mtv][r] += Ms[d * 32 + l31];
            }
        float inv = 1.f / (Ls[h * 32 + l31] + OTl[0]);      // halves are duplicates
        #pragma unroll
        for (int mtv = 0; mtv < 2; ++mtv)
            #pragma unroll
            for (int r = 0; r < 16; ++r) {
                int d = mtv * 32 + (r & 3) + 8 * (r >> 2) + 4 * h;
                Ts[l31 * 68 + d] = OT[mtv][r] * inv;
            }
    }
    __syncthreads();
    // all 256 threads: split-bf16 store of O into A-frag-major Ofrag
    {
        int q = tid >> 3, dc = (tid & 7) * 8;               // q 0..31
        float vv[8];
        #pragma unroll
        for (int i = 0; i < 8; ++i) vv[i] = Ts[q * 68 + dc + i];
        unsigned hi[4], lo[4];
        #pragma unroll
        for (int i = 0; i < 4; ++i) {
            float a = vv[2 * i], bb = vv[2 * i + 1];
            hi[i] = pk_trunc(a, bb);
            lo[i] = pk_trunc(a - tr16(a), bb - tr16(bb));
        }
        int ng = qt * 32 + q;                               // token within bh
        int r = bh * 256 + (ng >> 3);                       // gemm2 row
        int cc = (ng & 7) * 64 + dc;                        // gemm2 col (octet-aligned)
        int mt = r >> 4, m = r & 15, kc = cc >> 5, oct = (cc >> 3) & 3;
        unsigned short* fb_ = Ofrag + ((size_t)(mt * 16 + kc) * 2) * 512 + (m + 16 * oct) * 8;
        *(uint4*)fb_ = make_uint4(hi[0], hi[1], hi[2], hi[3]);
        *(uint4*)(fb_ + 512) = make_uint4(lo[0], lo[1], lo[2], lo[3]);
    }
}

// ---------------------------------------------------------------------------
// GEMM2: barrier-free, zero-LDS. Block = 64 rows x 64 cols; 4 waves (2x2),
// each 2 mt x 2 nt. grid (8, 64). out = Ofrag @ wpfrag + bias.
// ---------------------------------------------------------------------------
__global__ __launch_bounds__(256, 4) void gemm_proj(const unsigned short* __restrict__ Ofrag,
                                                    const unsigned short* __restrict__ wpfrag,
                                                    const float* __restrict__ bias,
                                                    float* __restrict__ out)
{
    const int tid = threadIdx.x, lane = tid & 63, w = tid >> 6;
    const int l15 = lane & 15, l4 = lane >> 4;
    const int row0 = blockIdx.y * 64, col0 = blockIdx.x * 64;
    const int wm = w >> 1, wn = w & 1;
    const int mt0 = (row0 >> 4) + wm * 2;
    const int nt0 = (col0 >> 4) + wn * 2;

    floatx4 acc[2][2];
    #pragma unroll
    for (int i = 0; i < 2; ++i)
        #pragma unroll
        for (int j = 0; j < 2; ++j)
            #pragma unroll
            for (int r = 0; r < 4; ++r) acc[i][j][r] = 0.f;

    const unsigned short* ab = Ofrag + (size_t)lane * 8;
    const unsigned short* wb = wpfrag + (size_t)lane * 8;

    #pragma unroll
    for (int kc = 0; kc < 16; ++kc) {
        short8 bf[2][2];
        #pragma unroll
        for (int nt = 0; nt < 2; ++nt) {
            size_t fb_ = ((size_t)((nt0 + nt) * 16 + kc) * 2) * 512;
            bf[nt][0] = bcs8(*(const uint4*)(wb + fb_));
            bf[nt][1] = bcs8(*(const uint4*)(wb + fb_ + 512));
        }
        #pragma unroll
        for (int mt = 0; mt < 2; ++mt) {
            size_t fa_ = ((size_t)((mt0 + mt) * 16 + kc) * 2) * 512;
            short8 ah = bcs8(*(const uint4*)(ab + fa_));
            short8 al = bcs8(*(const uint4*)(ab + fa_ + 512));
            #pragma unroll
            for (int nt = 0; nt < 2; ++nt) {
                acc[mt][nt] = mfma16(ah, bf[nt][0], acc[mt][nt]);
                acc[mt][nt] = mfma16(ah, bf[nt][1], acc[mt][nt]);
                acc[mt][nt] = mfma16(al, bf[nt][0], acc[mt][nt]);
            }
        }
    }
    #pragma unroll
    for (int mt = 0; mt < 2; ++mt)
        #pragma unroll
        for (int nt = 0; nt < 2; ++nt) {
            int c = col0 + wn * 32 + nt * 16 + l15;
            float bv = bias[c];
            #pragma unroll
            for (int r = 0; r < 4; ++r) {
                int tok = row0 + wm * 32 + mt * 16 + l4 * 4 + r;
                out[(size_t)tok * 512 + c] = acc[mt][nt][r] + bv;
            }
        }
}

// ---------------------------------------------------------------------------
extern "C" void kernel_launch(void* const* d_in, const int* in_sizes, int n_in,
                              void* d_out, int out_size, void* d_ws, size_t ws_size,
                              hipStream_t stream)
{
    const float* x      = (const float*)d_in[0];
    const float* qkv_w  = (const float*)d_in[1];
    const float* proj_w = (const float*)d_in[2];
    const float* proj_b = (const float*)d_in[3];
    float* out = (float*)d_out;

    char* ws = (char*)d_ws;
    unsigned short* xfrag  = (unsigned short*)ws;                     //  8 MiB
    unsigned short* wqfrag = (unsigned short*)(ws + 8388608);         //  3 MiB
    unsigned short* wpfrag = (unsigned short*)(ws + 11534336);        //  1 MiB
    unsigned short* qd     = (unsigned short*)(ws + 12582912);        //  4 MiB
    unsigned short* kfrag  = (unsigned short*)(ws + 16777216);        //  4 MiB
    unsigned short* vfrag  = (unsigned short*)(ws + 20971520);        //  4 MiB
    unsigned short* Ofrag  = (unsigned short*)(ws + 25165824);        //  8 MiB (end 32 MiB)

    prep<<<512, 256, 0, stream>>>(qkv_w, proj_w, x, wqfrag, wpfrag, xfrag);
    gemm_qkv<<<dim3(12, 64), 256, 0, stream>>>(xfrag, wqfrag, qd, kfrag, vfrag);
    attn<<<1024, 256, 0, stream>>>(qd, kfrag, vfrag, Ofrag);
    gemm_proj<<<dim3(8, 64), 256, 0, stream>>>(Ofrag, wpfrag, proj_b, out);
}